// Round 9
// baseline (304.826 us; speedup 1.0000x reference)
//
#include <hip/hip_runtime.h>
#include <hip/hip_bf16.h>
#include <math.h>

#define B_ROWS 1024
#define NT 8192
#define NS 8192
#define DIM 1024
#define NC 10
#define TEMP 100.0f
#define WCAP 1024   // sparse weight list capacity (selected weights)
#define CCAP 512    // per-row candidate capacity (expect ~64-100)
#define LTHR 18.421681f  // ln(1e8): candidate threshold below block-row max
#define PREP_RPB 8  // rows per block in k_prep0

typedef __bf16 bf16x8 __attribute__((ext_vector_type(8)));
typedef __bf16 bf16x4 __attribute__((ext_vector_type(4)));
typedef float f32x4 __attribute__((ext_vector_type(4)));

#define GLOAD_LDS(g, l) \
    __builtin_amdgcn_global_load_lds((__attribute__((address_space(1))) void*)(g), \
                                     (__attribute__((address_space(3))) void*)(l), 16, 0, 0)

__device__ inline __bf16 split_hi(float v) { return (__bf16)v; }
__device__ inline __bf16 split_lo(float v) {
    __bf16 h = (__bf16)v;
    return (__bf16)(v - (float)h);
}

// ---------------- reduction helpers ----------------
__device__ inline float wave_max(float v) {
    #pragma unroll
    for (int off = 32; off > 0; off >>= 1)
        v = fmaxf(v, __shfl_down(v, off, 64));
    return v;
}
__device__ inline float wave_sum(float v) {
    #pragma unroll
    for (int off = 32; off > 0; off >>= 1)
        v += __shfl_down(v, off, 64);
    return v;
}
__device__ inline float max4(float4 v) {
    return fmaxf(fmaxf(v.x, v.y), fmaxf(v.z, v.w));
}

// ---- K0: conv_norm(x|tf|sf) 8 rows/block + prep_labels + zero cnt ----------
__global__ __launch_bounds__(256) void k_prep0(const float* __restrict__ x,
                                               const float* __restrict__ tf,
                                               const float* __restrict__ sf,
                                               const float* __restrict__ sld,
                                               const float* __restrict__ shdl,
                                               const float* __restrict__ atl,
                                               __bf16* __restrict__ x2,
                                               __bf16* __restrict__ tf2,
                                               __bf16* __restrict__ sf2,
                                               float* __restrict__ nx_,
                                               float* __restrict__ nt_,
                                               float* __restrict__ ns_,
                                               float* __restrict__ M2Tt,
                                               float* __restrict__ atlt,
                                               int* __restrict__ cnt) {
    __shared__ float sred[4][PREP_RPB];
    __shared__ float sldL[NC * NC];
    const int NXB = B_ROWS / PREP_RPB;   // 128
    const int NTB = NT / PREP_RPB;       // 1024
    const int NSB = NS / PREP_RPB;       // 1024
    int b = blockIdx.x;
    int tid = threadIdx.x;
    if (b < NXB + NTB + NSB) {
        const float* Xp; __bf16* X2p; float* np; int r0;
        if (b < NXB)            { Xp = x;  X2p = x2;  np = nx_; r0 = b * PREP_RPB; }
        else if (b < NXB + NTB) { Xp = tf; X2p = tf2; np = nt_; r0 = (b - NXB) * PREP_RPB; }
        else                    { Xp = sf; X2p = sf2; np = ns_; r0 = (b - NXB - NTB) * PREP_RPB; }
        int c = tid * 4;
        int lane = tid & 63, wid = tid >> 6;
        #pragma unroll
        for (int r = 0; r < PREP_RPB; r++) {
            float4 v = *(const float4*)(Xp + (size_t)(r0 + r) * DIM + c);
            bf16x4 h, l;
            h[0] = split_hi(v.x); l[0] = split_lo(v.x);
            h[1] = split_hi(v.y); l[1] = split_lo(v.y);
            h[2] = split_hi(v.z); l[2] = split_lo(v.z);
            h[3] = split_hi(v.w); l[3] = split_lo(v.w);
            *(bf16x4*)(X2p + (size_t)(r0 + r) * 2048 + c) = h;
            *(bf16x4*)(X2p + (size_t)(r0 + r) * 2048 + 1024 + c) = l;
            float acc = v.x * v.x + v.y * v.y + v.z * v.z + v.w * v.w;
            float w = wave_sum(acc);
            if (lane == 0) sred[wid][r] = w;
        }
        __syncthreads();
        if (tid < PREP_RPB)
            np[r0 + tid] = sred[0][tid] + sred[1][tid] + sred[2][tid] + sred[3][tid];
    } else {
        if (b == NXB + NTB + NSB) {      // first label block also zeroes cnt
            #pragma unroll
            for (int z = 0; z < 4; z++) cnt[tid + z * 256] = 0;
        }
        if (tid < NC * NC) sldL[tid] = sld[tid];
        __syncthreads();
        int j = (b - NXB - NTB - NSB) * 256 + tid;
        float sh[NC], at[NC];
        #pragma unroll
        for (int k = 0; k < NC; k++) sh[k] = shdl[(size_t)j * NC + k];
        #pragma unroll
        for (int c = 0; c < NC; c++) at[c] = atl[(size_t)j * NC + c];
        #pragma unroll
        for (int c = 0; c < NC; c++) {
            float t = 0.f;
            #pragma unroll
            for (int k = 0; k < NC; k++) t += sldL[c * NC + k] * sh[k];
            M2Tt[c * NS + j] = t;
            atlt[c * NS + j] = at[c];
        }
    }
}

// ======== shared GEMM K-loop macro pieces (r8-proven 512-thread config) ======
// 128x128 tile, BK=64, sync-stage-sync, XOR chunk layout, 2 blocks/CU.

// ---- G3 kernel: logits -> S (unchanged r8 path) ----
__global__ __launch_bounds__(512, 4) void k_gemm3L(const __bf16* __restrict__ A2,
                                                   const __bf16* __restrict__ B2,
                                                   float* __restrict__ C,
                                                   int N, int K,
                                                   const float* __restrict__ rowN,
                                                   const float* __restrict__ colN) {
    __shared__ unsigned short AhS[8192], AlS[8192], BhS[8192], BlS[8192];
    __shared__ float extraL[256];
    float* rnL = extraL;
    float* cnL = extraL + 128;

    int tid = threadIdx.x;
    int wid = tid >> 6, lane = tid & 63;
    int wm = (wid >> 2) * 64, wn = (wid & 3) * 32;
    int id = blockIdx.y * gridDim.x + blockIdx.x;
    int bn_i = ((id >> 6) << 3) | (id & 7);
    int bm_i = (id >> 3) & 7;
    int bm = bm_i * 128, bn = bn_i * 128;
    size_t K2 = 2 * (size_t)K;
    int nsteps = K >> 6;

    if (tid < 128) rnL[tid] = rowN[bm + tid];
    else if (tid < 256) cnL[tid - 128] = colN[bn + tid - 128];

    f32x4 acc[4][2];
    #pragma unroll
    for (int i = 0; i < 4; i++)
        #pragma unroll
        for (int j = 0; j < 2; j++) acc[i][j] = (f32x4){0.f, 0.f, 0.f, 0.f};

    int arr = wid & 3, hh = wid >> 2;
    char* arrB = (arr == 0) ? (char*)AhS : (arr == 1) ? (char*)AlS
               : (arr == 2) ? (char*)BhS : (char*)BlS;
    const __bf16* gbase = (arr < 2) ? A2 : B2;
    int rbase = (arr < 2) ? bm : bn;
    int hilo = (arr & 1) ? K : 0;
    int r_in = lane >> 3;
    int cgo = ((lane & 7) ^ r_in) * 8;
    const __bf16* gw = gbase + (size_t)(rbase + hh * 64 + r_in) * K2 + hilo + cgo;
    int ldst = hh * 8192;
    size_t row8 = 8 * K2;

    int ra = lane & 15, q = lane >> 4;
    int aoff[4][2], boff[2][2];
    #pragma unroll
    for (int kh = 0; kh < 2; kh++) {
        #pragma unroll
        for (int i = 0; i < 4; i++) {
            int chunk = ((kh << 2) | q) ^ (ra & 7);
            aoff[i][kh] = (wm + i * 16 + ra) * 64 + chunk * 8;
        }
        #pragma unroll
        for (int j = 0; j < 2; j++) {
            int chunk = ((kh << 2) | q) ^ (ra & 7);
            boff[j][kh] = (wn + j * 16 + ra) * 64 + chunk * 8;
        }
    }
    const __bf16* AhE = (const __bf16*)AhS;
    const __bf16* AlE = (const __bf16*)AlS;
    const __bf16* BhE = (const __bf16*)BhS;
    const __bf16* BlE = (const __bf16*)BlS;

    for (int ks = 0; ks < nsteps; ks++) {
        __syncthreads();
        #pragma unroll
        for (int p = 0; p < 8; p++)
            GLOAD_LDS(gw + (size_t)p * row8, arrB + ldst + p * 1024);
        gw += 64;
        __syncthreads();
        #pragma unroll
        for (int kh = 0; kh < 2; kh++) {
            bf16x8 ah[4], al[4];
            #pragma unroll
            for (int mi = 0; mi < 4; mi++) {
                ah[mi] = *(const bf16x8*)(AhE + aoff[mi][kh]);
                al[mi] = *(const bf16x8*)(AlE + aoff[mi][kh]);
            }
            #pragma unroll
            for (int ni = 0; ni < 2; ni++) {
                bf16x8 bh = *(const bf16x8*)(BhE + boff[ni][kh]);
                bf16x8 bl = *(const bf16x8*)(BlE + boff[ni][kh]);
                #pragma unroll
                for (int mi = 0; mi < 4; mi++) {
                    acc[mi][ni] = __builtin_amdgcn_mfma_f32_16x16x32_bf16(ah[mi], bh, acc[mi][ni], 0, 0, 0);
                    acc[mi][ni] = __builtin_amdgcn_mfma_f32_16x16x32_bf16(ah[mi], bl, acc[mi][ni], 0, 0, 0);
                    acc[mi][ni] = __builtin_amdgcn_mfma_f32_16x16x32_bf16(al[mi], bh, acc[mi][ni], 0, 0, 0);
                }
            }
        }
    }

    #pragma unroll
    for (int mi = 0; mi < 4; mi++) {
        #pragma unroll
        for (int ni = 0; ni < 2; ni++) {
            int cl = wn + ni * 16 + ra;
            float cn = cnL[cl];
            #pragma unroll
            for (int i = 0; i < 4; i++) {
                int rl = wm + mi * 16 + q * 4 + i;
                float sq = rnL[rl] + cn - 2.f * acc[mi][ni][i];
                float d = sqrtf(fmaxf(sq, 1e-12f));
                C[(size_t)(bm + rl) * N + bn + cl] = -TEMP * d;
            }
        }
    }
}

// ---- G1 kernel: partial softmax stats + candidate list (NO S write) --------
// Per row r, column-block b: ms[r][b] = (m_b, s_b) with m_b = tile row max,
// s_b = sum e^(l-m_b) over tile; candidates = cols with l > m_b - ln(1e8)
// (superset of all true weights > 1e-8 since m_b <= global M, sum >= 1).
__global__ __launch_bounds__(512, 4) void k_gemm_part(const __bf16* __restrict__ A2,
                                                      const __bf16* __restrict__ B2,
                                                      int N, int K,
                                                      const float* __restrict__ rowN,
                                                      const float* __restrict__ colN,
                                                      float2* __restrict__ ms,
                                                      int* __restrict__ cnt,
                                                      int* __restrict__ candj,
                                                      float* __restrict__ candl) {
    __shared__ unsigned short AhS[8192], AlS[8192], BhS[8192], BlS[8192];
    __shared__ float extraL[256];
    __shared__ float mred[128][4];
    __shared__ float sredL[128][4];
    float* rnL = extraL;
    float* cnL = extraL + 128;

    int tid = threadIdx.x;
    int wid = tid >> 6, lane = tid & 63;
    int wm = (wid >> 2) * 64, wn = (wid & 3) * 32;
    int id = blockIdx.y * gridDim.x + blockIdx.x;
    int bn_i = ((id >> 6) << 3) | (id & 7);
    int bm_i = (id >> 3) & 7;
    int bm = bm_i * 128, bn = bn_i * 128;
    size_t K2 = 2 * (size_t)K;
    int nsteps = K >> 6;

    if (tid < 128) rnL[tid] = rowN[bm + tid];
    else if (tid < 256) cnL[tid - 128] = colN[bn + tid - 128];

    f32x4 acc[4][2];
    #pragma unroll
    for (int i = 0; i < 4; i++)
        #pragma unroll
        for (int j = 0; j < 2; j++) acc[i][j] = (f32x4){0.f, 0.f, 0.f, 0.f};

    int arr = wid & 3, hh = wid >> 2;
    char* arrB = (arr == 0) ? (char*)AhS : (arr == 1) ? (char*)AlS
               : (arr == 2) ? (char*)BhS : (char*)BlS;
    const __bf16* gbase = (arr < 2) ? A2 : B2;
    int rbase = (arr < 2) ? bm : bn;
    int hilo = (arr & 1) ? K : 0;
    int r_in = lane >> 3;
    int cgo = ((lane & 7) ^ r_in) * 8;
    const __bf16* gw = gbase + (size_t)(rbase + hh * 64 + r_in) * K2 + hilo + cgo;
    int ldst = hh * 8192;
    size_t row8 = 8 * K2;

    int ra = lane & 15, q = lane >> 4;
    int aoff[4][2], boff[2][2];
    #pragma unroll
    for (int kh = 0; kh < 2; kh++) {
        #pragma unroll
        for (int i = 0; i < 4; i++) {
            int chunk = ((kh << 2) | q) ^ (ra & 7);
            aoff[i][kh] = (wm + i * 16 + ra) * 64 + chunk * 8;
        }
        #pragma unroll
        for (int j = 0; j < 2; j++) {
            int chunk = ((kh << 2) | q) ^ (ra & 7);
            boff[j][kh] = (wn + j * 16 + ra) * 64 + chunk * 8;
        }
    }
    const __bf16* AhE = (const __bf16*)AhS;
    const __bf16* AlE = (const __bf16*)AlS;
    const __bf16* BhE = (const __bf16*)BhS;
    const __bf16* BlE = (const __bf16*)BlS;

    for (int ks = 0; ks < nsteps; ks++) {
        __syncthreads();
        #pragma unroll
        for (int p = 0; p < 8; p++)
            GLOAD_LDS(gw + (size_t)p * row8, arrB + ldst + p * 1024);
        gw += 64;
        __syncthreads();
        #pragma unroll
        for (int kh = 0; kh < 2; kh++) {
            bf16x8 ah[4], al[4];
            #pragma unroll
            for (int mi = 0; mi < 4; mi++) {
                ah[mi] = *(const bf16x8*)(AhE + aoff[mi][kh]);
                al[mi] = *(const bf16x8*)(AlE + aoff[mi][kh]);
            }
            #pragma unroll
            for (int ni = 0; ni < 2; ni++) {
                bf16x8 bh = *(const bf16x8*)(BhE + boff[ni][kh]);
                bf16x8 bl = *(const bf16x8*)(BlE + boff[ni][kh]);
                #pragma unroll
                for (int mi = 0; mi < 4; mi++) {
                    acc[mi][ni] = __builtin_amdgcn_mfma_f32_16x16x32_bf16(ah[mi], bh, acc[mi][ni], 0, 0, 0);
                    acc[mi][ni] = __builtin_amdgcn_mfma_f32_16x16x32_bf16(ah[mi], bl, acc[mi][ni], 0, 0, 0);
                    acc[mi][ni] = __builtin_amdgcn_mfma_f32_16x16x32_bf16(al[mi], bh, acc[mi][ni], 0, 0, 0);
                }
            }
        }
    }

    // ---- epilogue: logits in registers, wave row-reduce, block partials ----
    float lv[4][2][4];
    #pragma unroll
    for (int mi = 0; mi < 4; mi++) {
        #pragma unroll
        for (int ni = 0; ni < 2; ni++) {
            float cn = cnL[wn + ni * 16 + ra];
            #pragma unroll
            for (int i = 0; i < 4; i++) {
                int rl = wm + mi * 16 + q * 4 + i;
                float sq = rnL[rl] + cn - 2.f * acc[mi][ni][i];
                lv[mi][ni][i] = -TEMP * sqrtf(fmaxf(sq, 1e-12f));
            }
        }
    }
    int cw = wid & 3;                    // column-wave index
    #pragma unroll
    for (int mi = 0; mi < 4; mi++) {
        #pragma unroll
        for (int i = 0; i < 4; i++) {
            float v = fmaxf(lv[mi][0][i], lv[mi][1][i]);
            #pragma unroll
            for (int off = 1; off < 16; off <<= 1)
                v = fmaxf(v, __shfl_xor(v, off, 64));
            float p = __expf(lv[mi][0][i] - v) + __expf(lv[mi][1][i] - v);
            #pragma unroll
            for (int off = 1; off < 16; off <<= 1)
                p += __shfl_xor(p, off, 64);
            if (ra == 0) {
                int rl = wm + mi * 16 + q * 4 + i;
                mred[rl][cw] = v;
                sredL[rl][cw] = p;
            }
        }
    }
    __syncthreads();
    if (tid < 128) {                     // per-row block stats -> global
        float4 mv = *(const float4*)mred[tid];
        float m = max4(mv);
        float4 sv = *(const float4*)sredL[tid];
        float s = sv.x * __expf(mv.x - m) + sv.y * __expf(mv.y - m)
                + sv.z * __expf(mv.z - m) + sv.w * __expf(mv.w - m);
        ms[(size_t)(bm + tid) * 64 + bn_i] = make_float2(m, s);
    }
    // candidates vs block-row max
    #pragma unroll
    for (int mi = 0; mi < 4; mi++) {
        #pragma unroll
        for (int i = 0; i < 4; i++) {
            int rl = wm + mi * 16 + q * 4 + i;
            float thr = max4(*(const float4*)mred[rl]) - LTHR;
            #pragma unroll
            for (int ni = 0; ni < 2; ni++) {
                if (lv[mi][ni][i] > thr) {
                    int gr = bm + rl;
                    int k = atomicAdd(&cnt[gr], 1);
                    if (k < CCAP) {
                        candj[(size_t)gr * CCAP + k] = bn + wn + ni * 16 + ra;
                        candl[(size_t)gr * CCAP + k] = lv[mi][ni][i];
                    }
                }
            }
        }
    }
}

// ---- k_xsrc: exact softmax from partials + candidate eval + sparse gather --
__global__ __launch_bounds__(256) void k_xsrc(const float2* __restrict__ ms,
                                              const int* __restrict__ cnt,
                                              const int* __restrict__ candj,
                                              const float* __restrict__ candl,
                                              const float* __restrict__ asf,
                                              const float* __restrict__ W,
                                              const float* __restrict__ bias,
                                              __bf16* __restrict__ xsrc2,
                                              float* __restrict__ nx2_,
                                              float* __restrict__ preds) {
    __shared__ float sm[4];
    __shared__ float ss[4];
    __shared__ int   sidx[WCAP];
    __shared__ float swt[WCAP];
    __shared__ int   scnt;
    __shared__ float red[4][NC + 1];
    int row = blockIdx.x;
    int tid = threadIdx.x;
    int lane = tid & 63, wid = tid >> 6;
    if (tid == 0) scnt = 0;
    // all 4 waves redundantly reduce the 64 block partials
    float2 msv = ms[(size_t)row * 64 + lane];
    float wmx = wave_max(msv.x);
    if (lane == 0) sm[wid] = wmx;
    __syncthreads();                     // also covers scnt=0
    float M = fmaxf(fmaxf(sm[0], sm[1]), fmaxf(sm[2], sm[3]));
    float sp = msv.y * __expf(msv.x - M);
    float wsv = wave_sum(sp);
    if (lane == 0) ss[wid] = wsv;
    __syncthreads();
    float inv = 1.0f / ss[0];            // each wave computed the full sum
    int n = cnt[row]; n = n < CCAP ? n : CCAP;
    for (int i = tid; i < n; i += 256) {
        float w = __expf(candl[(size_t)row * CCAP + i] - M) * inv;
        if (w > 1e-8f) {
            int k = atomicAdd(&scnt, 1);
            if (k < WCAP) { sidx[k] = candj[(size_t)row * CCAP + i]; swt[k] = w; }
        }
    }
    __syncthreads();
    int cw = scnt < WCAP ? scnt : WCAP;
    int c = tid * 4;
    float sx = 0.f, sy = 0.f, sz = 0.f, sw = 0.f;
    for (int i = 0; i < cw; i++) {
        float wg = swt[i];
        float4 v = *(const float4*)(asf + (size_t)sidx[i] * DIM + c);
        sx += wg * v.x; sy += wg * v.y; sz += wg * v.z; sw += wg * v.w;
    }
    // ---- fused epilogue: split + norm + preds ----
    bf16x4 h, l;
    h[0] = split_hi(sx); l[0] = split_lo(sx);
    h[1] = split_hi(sy); l[1] = split_lo(sy);
    h[2] = split_hi(sz); l[2] = split_lo(sz);
    h[3] = split_hi(sw); l[3] = split_lo(sw);
    *(bf16x4*)(xsrc2 + (size_t)row * 2048 + c) = h;
    *(bf16x4*)(xsrc2 + (size_t)row * 2048 + 1024 + c) = l;
    float accn = sx * sx + sy * sy + sz * sz + sw * sw;
    float accp[NC];
    #pragma unroll
    for (int cc = 0; cc < NC; cc++)
        accp[cc] = sx * W[(c + 0) * NC + cc] + sy * W[(c + 1) * NC + cc]
                 + sz * W[(c + 2) * NC + cc] + sw * W[(c + 3) * NC + cc];
    accn = wave_sum(accn);
    #pragma unroll
    for (int cc = 0; cc < NC; cc++) accp[cc] = wave_sum(accp[cc]);
    if (lane == 0) {
        red[wid][0] = accn;
        #pragma unroll
        for (int cc = 0; cc < NC; cc++) red[wid][1 + cc] = accp[cc];
    }
    __syncthreads();
    if (tid == 0) {
        nx2_[row] = red[0][0] + red[1][0] + red[2][0] + red[3][0];
        float lo[NC];
        float m = -1e30f;
        #pragma unroll
        for (int cc = 0; cc < NC; cc++) {
            lo[cc] = red[0][1 + cc] + red[1][1 + cc] + red[2][1 + cc] + red[3][1 + cc]
                   + bias[cc];
            m = fmaxf(m, lo[cc]);
        }
        float ssum = 0.f;
        #pragma unroll
        for (int cc = 0; cc < NC; cc++) {
            lo[cc] = __expf(lo[cc] - m);
            ssum += lo[cc];
        }
        float iv = 1.0f / ssum;
        #pragma unroll
        for (int cc = 0; cc < NC; cc++) preds[(size_t)row * NC + cc] = lo[cc] * iv;
    }
}

// ------- label softmax + y, 2 rows/block, float4-vectorized ------------------
__global__ __launch_bounds__(256) void k_lab_softmax_y(const float* __restrict__ S,
                                                       const float* __restrict__ predsG,
                                                       const float* __restrict__ M2Tt,
                                                       const float* __restrict__ atlt,
                                                       float* __restrict__ y) {
    int r0 = blockIdx.x * 2, r1 = r0 + 1;
    float pr0[NC], pr1[NC];
    #pragma unroll
    for (int c = 0; c < NC; c++) {
        pr0[c] = TEMP * predsG[(size_t)r0 * NC + c];
        pr1[c] = TEMP * predsG[(size_t)r1 * NC + c];
    }
    const float4* s0 = (const float4*)(S + (size_t)r0 * NS);
    const float4* s1 = (const float4*)(S + (size_t)r1 * NS);
    const float4* M2 = (const float4*)M2Tt;    // [NC][2048]
    const float4* AT = (const float4*)atlt;    // [NC][2048]
    float4 v0[NS / 1024], v1[NS / 1024];       // 8 each
    float m0 = -1e30f, m1 = -1e30f;
    #pragma unroll
    for (int u = 0; u < NS / 1024; u++) {
        int j4 = threadIdx.x + u * 256;
        float4 a = s0[j4], b = s1[j4];
        float4 lab0 = make_float4(0.f, 0.f, 0.f, 0.f);
        float4 lab1 = make_float4(0.f, 0.f, 0.f, 0.f);
        #pragma unroll
        for (int c = 0; c < NC; c++) {
            float4 mv = M2[c * 2048 + j4];
            lab0.x += pr0[c] * mv.x; lab0.y += pr0[c] * mv.y;
            lab0.z += pr0[c] * mv.z; lab0.w += pr0[c] * mv.w;
            lab1.x += pr1[c] * mv.x; lab1.y += pr1[c] * mv.y;
            lab1.z += pr1[c] * mv.z; lab1.w += pr1[c] * mv.w;
        }
        a.x -= lab0.x; a.y -= lab0.y;
        a.z -= lab0.z; a.w -= lab0.w;
        b.x -= lab1.x; b.y -= lab1.y;
        b.z -= lab1.z; b.w -= lab1.w;
        v0[u] = a; v1[u] = b;
        m0 = fmaxf(m0, fmaxf(fmaxf(a.x, a.y), fmaxf(a.z, a.w)));
        m1 = fmaxf(m1, fmaxf(fmaxf(b.x, b.y), fmaxf(b.z, b.w)));
    }
    __shared__ float sm[2][4];
    __shared__ float ss[2][4];
    __shared__ float yred[4][2][NC];
    int lane = threadIdx.x & 63, wid = threadIdx.x >> 6;
    float wm0 = wave_max(m0), wm1 = wave_max(m1);
    if (lane == 0) { sm[0][wid] = wm0; sm[1][wid] = wm1; }
    __syncthreads();
    float bm0 = fmaxf(fmaxf(sm[0][0], sm[0][1]), fmaxf(sm[0][2], sm[0][3]));
    float bm1 = fmaxf(fmaxf(sm[1][0], sm[1][1]), fmaxf(sm[1][2], sm[1][3]));
    float ls0 = 0.f, ls1 = 0.f;
    #pragma unroll
    for (int u = 0; u < NS / 1024; u++) {
        float4 a = v0[u], b = v1[u];
        a.x = __expf(a.x - bm0); a.y = __expf(a.y - bm0);
        a.z = __expf(a.z - bm0); a.w = __expf(a.w - bm0);
        b.x = __expf(b.x - bm1); b.y = __expf(b.y - bm1);
        b.z = __expf(b.z - bm1); b.w = __expf(b.w - bm1);
        v0[u] = a; v1[u] = b;
        ls0 += a.x + a.y + a.z + a.w;
        ls1 += b.x + b.y + b.z + b.w;
    }
    float ws0 = wave_sum(ls0), ws1 = wave_sum(ls1);
    if (lane == 0) { ss[0][wid] = ws0; ss[1][wid] = ws1; }
    __syncthreads();
    float inv0 = 1.0f / (ss[0][0] + ss[0][1] + ss[0][2] + ss[0][3]);
    float inv1 = 1.0f / (ss[1][0] + ss[1][1] + ss[1][2] + ss[1][3]);
    float y0[NC] = {}, y1[NC] = {};
    #pragma unroll
    for (int u = 0; u < NS / 1024; u++) {
        int j4 = threadIdx.x + u * 256;
        float4 a = v0[u], b = v1[u];
        #pragma unroll
        for (int c = 0; c < NC; c++) {
            float4 av = AT[c * 2048 + j4];
            y0[c] += a.x * av.x + a.y * av.y + a.z * av.z + a.w * av.w;
            y1[c] += b.x * av.x + b.y * av.y + b.z * av.z + b.w * av.w;
        }
    }
    #pragma unroll
    for (int c = 0; c < NC; c++) {
        y0[c] = wave_sum(y0[c]) * inv0;
        y1[c] = wave_sum(y1[c]) * inv1;
    }
    if (lane == 0) {
        #pragma unroll
        for (int c = 0; c < NC; c++) { yred[wid][0][c] = y0[c]; yred[wid][1][c] = y1[c]; }
    }
    __syncthreads();
    if (threadIdx.x < 2 * NC) {
        int r = threadIdx.x / NC, c = threadIdx.x - r * NC;
        y[(size_t)(r0 + r) * NC + c] = yred[0][r][c] + yred[1][r][c] + yred[2][r][c] + yred[3][r][c];
    }
}

extern "C" void kernel_launch(void* const* d_in, const int* in_sizes, int n_in,
                              void* d_out, int out_size, void* d_ws, size_t ws_size,
                              hipStream_t stream) {
    const float* x    = (const float*)d_in[0];   // [1024, 32, 32]
    const float* tf   = (const float*)d_in[1];   // [8192, 1024]
    const float* asf  = (const float*)d_in[2];   // [8192, 1024]
    const float* sf   = (const float*)d_in[3];   // [8192, 1024]
    const float* shdl = (const float*)d_in[4];   // [8192, 10]
    const float* atl  = (const float*)d_in[5];   // [8192, 10]
    const float* sld  = (const float*)d_in[6];   // [10, 10]
    const float* W    = (const float*)d_in[7];   // [1024, 10]
    const float* bias = (const float*)d_in[8];   // [10]
    float* y = (float*)d_out;                    // [1024, 10]

    char* wsb = (char*)d_ws;
    // Region lifetimes:
    //  R0 @0 (32 MiB): [G1 phase] candj(2M) candl(2M) ms(512K) cnt(4K)
    //                  [G3 phase] S (32 MiB) - overwrites cand data (dead)
    //  R1 @32 (32 MiB): tf2 (dead after G1)
    //  R2 @64 (32 MiB): sf2 (written by k_prep0, read by G3)
    int*    candj = (int*)(wsb);
    float*  candl = (float*)(wsb + (2u << 20));
    float2* ms    = (float2*)(wsb + (4u << 20));
    int*    cnt   = (int*)(wsb + (4u << 20) + (512u << 10));
    float*  S     = (float*)(wsb);
    __bf16* tf2   = (__bf16*)(wsb + (32u << 20));
    __bf16* sf2   = (__bf16*)(wsb + (64u << 20));
    __bf16* x2    = (__bf16*)(wsb + (96u << 20));           // 4 MiB
    __bf16* xsrc2 = (__bf16*)(wsb + (100u << 20));          // 4 MiB
    float*  nt_   = (float*)(wsb + (108u << 20));
    float*  ns_   = nt_ + NT;
    float*  nx_   = ns_ + NS;
    float*  nx2_  = nx_ + B_ROWS;
    float*  preds = nx2_ + B_ROWS;
    float*  M2Tt  = preds + B_ROWS * NC;                    // [10][8192]
    float*  atlt  = M2Tt + NS * NC;                         // [10][8192]

    // K0: conv_norm(x|tf|sf) 8 rows/block + prep_labels + zero cnt
    {
        int nblk = B_ROWS / PREP_RPB + NT / PREP_RPB + NS / PREP_RPB + NS / 256;
        k_prep0<<<nblk, 256, 0, stream>>>(x, tf, sf, sld, shdl, atl,
                                          x2, tf2, sf2, nx_, nt_, ns_, M2Tt, atlt,
                                          cnt);
    }

    // G1 (partial): per-block softmax stats + candidates; no S materialization
    {
        dim3 g(NT / 128, B_ROWS / 128, 1);
        k_gemm_part<<<g, 512, 0, stream>>>(x2, tf2, NT, DIM, nx_, nt_,
                                           ms, cnt, candj, candl);
    }

    // k_xsrc: exact softmax merge + sparse gather (reads ~5 MB, was 32 MB)
    k_xsrc<<<B_ROWS, 256, 0, stream>>>(ms, cnt, candj, candl, asf, W, bias,
                                       xsrc2, nx2_, preds);

    // G3: S = logits(-TEMP*d(xsrc, sf))  (M=1024, N=8192, K=1024) -> R0
    {
        dim3 g(NS / 128, B_ROWS / 128, 1);
        k_gemm3L<<<g, 512, 0, stream>>>(xsrc2, sf2, S, NS, DIM, nx2_, ns_);
    }
    // label softmax (with M2T term) + y, 2 rows/block (vectorized)
    k_lab_softmax_y<<<B_ROWS / 2, 256, 0, stream>>>(S, preds, M2Tt, atlt, y);
}

// Round 10
// 284.054 us; speedup vs baseline: 1.0731x; 1.0731x over previous
//
#include <hip/hip_runtime.h>
#include <hip/hip_bf16.h>
#include <math.h>

#define B_ROWS 1024
#define NT 8192
#define NS 8192
#define DIM 1024
#define NC 10
#define TEMP 100.0f
#define WCAP 1024   // sparse weight list capacity (selected weights)
#define CCAP 512    // per-row candidate capacity (expect ~64-192)
#define LTHR 18.421681f  // ln(1e8): candidate threshold below block-row max
#define PREP_RPB 8  // rows per block in k_prep0
#define TSTR 132    // logit tile row stride (floats): 128+4 -> <=4-way conflicts

typedef __bf16 bf16x8 __attribute__((ext_vector_type(8)));
typedef __bf16 bf16x4 __attribute__((ext_vector_type(4)));
typedef float f32x4 __attribute__((ext_vector_type(4)));

#define GLOAD_LDS(g, l) \
    __builtin_amdgcn_global_load_lds((__attribute__((address_space(1))) void*)(g), \
                                     (__attribute__((address_space(3))) void*)(l), 16, 0, 0)

__device__ inline __bf16 split_hi(float v) { return (__bf16)v; }
__device__ inline __bf16 split_lo(float v) {
    __bf16 h = (__bf16)v;
    return (__bf16)(v - (float)h);
}

// ---------------- reduction helpers ----------------
__device__ inline float wave_max(float v) {
    #pragma unroll
    for (int off = 32; off > 0; off >>= 1)
        v = fmaxf(v, __shfl_down(v, off, 64));
    return v;
}
__device__ inline float wave_sum(float v) {
    #pragma unroll
    for (int off = 32; off > 0; off >>= 1)
        v += __shfl_down(v, off, 64);
    return v;
}
__device__ inline float max4(float4 v) {
    return fmaxf(fmaxf(v.x, v.y), fmaxf(v.z, v.w));
}

// ---- K0: conv_norm(x|tf|sf) 8 rows/block + prep_labels + zero cnt ----------
__global__ __launch_bounds__(256) void k_prep0(const float* __restrict__ x,
                                               const float* __restrict__ tf,
                                               const float* __restrict__ sf,
                                               const float* __restrict__ sld,
                                               const float* __restrict__ shdl,
                                               const float* __restrict__ atl,
                                               __bf16* __restrict__ x2,
                                               __bf16* __restrict__ tf2,
                                               __bf16* __restrict__ sf2,
                                               float* __restrict__ nx_,
                                               float* __restrict__ nt_,
                                               float* __restrict__ ns_,
                                               float* __restrict__ M2Tt,
                                               float* __restrict__ atlt,
                                               int* __restrict__ cnt) {
    __shared__ float sred[4][PREP_RPB];
    __shared__ float sldL[NC * NC];
    const int NXB = B_ROWS / PREP_RPB;   // 128
    const int NTB = NT / PREP_RPB;       // 1024
    const int NSB = NS / PREP_RPB;       // 1024
    int b = blockIdx.x;
    int tid = threadIdx.x;
    if (b < NXB + NTB + NSB) {
        const float* Xp; __bf16* X2p; float* np; int r0;
        if (b < NXB)            { Xp = x;  X2p = x2;  np = nx_; r0 = b * PREP_RPB; }
        else if (b < NXB + NTB) { Xp = tf; X2p = tf2; np = nt_; r0 = (b - NXB) * PREP_RPB; }
        else                    { Xp = sf; X2p = sf2; np = ns_; r0 = (b - NXB - NTB) * PREP_RPB; }
        int c = tid * 4;
        int lane = tid & 63, wid = tid >> 6;
        #pragma unroll
        for (int r = 0; r < PREP_RPB; r++) {
            float4 v = *(const float4*)(Xp + (size_t)(r0 + r) * DIM + c);
            bf16x4 h, l;
            h[0] = split_hi(v.x); l[0] = split_lo(v.x);
            h[1] = split_hi(v.y); l[1] = split_lo(v.y);
            h[2] = split_hi(v.z); l[2] = split_lo(v.z);
            h[3] = split_hi(v.w); l[3] = split_lo(v.w);
            *(bf16x4*)(X2p + (size_t)(r0 + r) * 2048 + c) = h;
            *(bf16x4*)(X2p + (size_t)(r0 + r) * 2048 + 1024 + c) = l;
            float acc = v.x * v.x + v.y * v.y + v.z * v.z + v.w * v.w;
            float w = wave_sum(acc);
            if (lane == 0) sred[wid][r] = w;
        }
        __syncthreads();
        if (tid < PREP_RPB)
            np[r0 + tid] = sred[0][tid] + sred[1][tid] + sred[2][tid] + sred[3][tid];
    } else {
        if (b == NXB + NTB + NSB) {      // first label block also zeroes cnt
            #pragma unroll
            for (int z = 0; z < 4; z++) cnt[tid + z * 256] = 0;
        }
        if (tid < NC * NC) sldL[tid] = sld[tid];
        __syncthreads();
        int j = (b - NXB - NTB - NSB) * 256 + tid;
        float sh[NC], at[NC];
        #pragma unroll
        for (int k = 0; k < NC; k++) sh[k] = shdl[(size_t)j * NC + k];
        #pragma unroll
        for (int c = 0; c < NC; c++) at[c] = atl[(size_t)j * NC + c];
        #pragma unroll
        for (int c = 0; c < NC; c++) {
            float t = 0.f;
            #pragma unroll
            for (int k = 0; k < NC; k++) t += sldL[c * NC + k] * sh[k];
            M2Tt[c * NS + j] = t;
            atlt[c * NS + j] = at[c];
        }
    }
}

// ======== r8-proven GEMM core: 128x128 tile, BK=64, 512 threads, 2 blk/CU ===

// ---- G3 kernel: logits -> S (unchanged r8 path) ----
__global__ __launch_bounds__(512, 4) void k_gemm3L(const __bf16* __restrict__ A2,
                                                   const __bf16* __restrict__ B2,
                                                   float* __restrict__ C,
                                                   int N, int K,
                                                   const float* __restrict__ rowN,
                                                   const float* __restrict__ colN) {
    __shared__ unsigned short AhS[8192], AlS[8192], BhS[8192], BlS[8192];
    __shared__ float extraL[256];
    float* rnL = extraL;
    float* cnL = extraL + 128;

    int tid = threadIdx.x;
    int wid = tid >> 6, lane = tid & 63;
    int wm = (wid >> 2) * 64, wn = (wid & 3) * 32;
    int id = blockIdx.y * gridDim.x + blockIdx.x;
    int bn_i = ((id >> 6) << 3) | (id & 7);
    int bm_i = (id >> 3) & 7;
    int bm = bm_i * 128, bn = bn_i * 128;
    size_t K2 = 2 * (size_t)K;
    int nsteps = K >> 6;

    if (tid < 128) rnL[tid] = rowN[bm + tid];
    else if (tid < 256) cnL[tid - 128] = colN[bn + tid - 128];

    f32x4 acc[4][2];
    #pragma unroll
    for (int i = 0; i < 4; i++)
        #pragma unroll
        for (int j = 0; j < 2; j++) acc[i][j] = (f32x4){0.f, 0.f, 0.f, 0.f};

    int arr = wid & 3, hh = wid >> 2;
    char* arrB = (arr == 0) ? (char*)AhS : (arr == 1) ? (char*)AlS
               : (arr == 2) ? (char*)BhS : (char*)BlS;
    const __bf16* gbase = (arr < 2) ? A2 : B2;
    int rbase = (arr < 2) ? bm : bn;
    int hilo = (arr & 1) ? K : 0;
    int r_in = lane >> 3;
    int cgo = ((lane & 7) ^ r_in) * 8;
    const __bf16* gw = gbase + (size_t)(rbase + hh * 64 + r_in) * K2 + hilo + cgo;
    int ldst = hh * 8192;
    size_t row8 = 8 * K2;

    int ra = lane & 15, q = lane >> 4;
    int aoff[4][2], boff[2][2];
    #pragma unroll
    for (int kh = 0; kh < 2; kh++) {
        #pragma unroll
        for (int i = 0; i < 4; i++) {
            int chunk = ((kh << 2) | q) ^ (ra & 7);
            aoff[i][kh] = (wm + i * 16 + ra) * 64 + chunk * 8;
        }
        #pragma unroll
        for (int j = 0; j < 2; j++) {
            int chunk = ((kh << 2) | q) ^ (ra & 7);
            boff[j][kh] = (wn + j * 16 + ra) * 64 + chunk * 8;
        }
    }
    const __bf16* AhE = (const __bf16*)AhS;
    const __bf16* AlE = (const __bf16*)AlS;
    const __bf16* BhE = (const __bf16*)BhS;
    const __bf16* BlE = (const __bf16*)BlS;

    for (int ks = 0; ks < nsteps; ks++) {
        __syncthreads();
        #pragma unroll
        for (int p = 0; p < 8; p++)
            GLOAD_LDS(gw + (size_t)p * row8, arrB + ldst + p * 1024);
        gw += 64;
        __syncthreads();
        #pragma unroll
        for (int kh = 0; kh < 2; kh++) {
            bf16x8 ah[4], al[4];
            #pragma unroll
            for (int mi = 0; mi < 4; mi++) {
                ah[mi] = *(const bf16x8*)(AhE + aoff[mi][kh]);
                al[mi] = *(const bf16x8*)(AlE + aoff[mi][kh]);
            }
            #pragma unroll
            for (int ni = 0; ni < 2; ni++) {
                bf16x8 bh = *(const bf16x8*)(BhE + boff[ni][kh]);
                bf16x8 bl = *(const bf16x8*)(BlE + boff[ni][kh]);
                #pragma unroll
                for (int mi = 0; mi < 4; mi++) {
                    acc[mi][ni] = __builtin_amdgcn_mfma_f32_16x16x32_bf16(ah[mi], bh, acc[mi][ni], 0, 0, 0);
                    acc[mi][ni] = __builtin_amdgcn_mfma_f32_16x16x32_bf16(ah[mi], bl, acc[mi][ni], 0, 0, 0);
                    acc[mi][ni] = __builtin_amdgcn_mfma_f32_16x16x32_bf16(al[mi], bh, acc[mi][ni], 0, 0, 0);
                }
            }
        }
    }

    #pragma unroll
    for (int mi = 0; mi < 4; mi++) {
        #pragma unroll
        for (int ni = 0; ni < 2; ni++) {
            int cl = wn + ni * 16 + ra;
            float cn = cnL[cl];
            #pragma unroll
            for (int i = 0; i < 4; i++) {
                int rl = wm + mi * 16 + q * 4 + i;
                float sq = rnL[rl] + cn - 2.f * acc[mi][ni][i];
                float d = sqrtf(fmaxf(sq, 1e-12f));
                C[(size_t)(bm + rl) * N + bn + cl] = -TEMP * d;
            }
        }
    }
}

// ---- G1 kernel: partial softmax stats + candidates, LDS-tile epilogue -------
// Per row r, column-block b: ms[r][b]=(m_b,s_b); candidates: l > m_b - ln(1e8)
// (superset of true weights > 1e-8). Epilogue writes logits to an LDS tile
// (union with dead staging arrays; stride 132 floats), then 4 threads/row scan
// it: NO register lv array (r9: scratch spill), only 4 shfl_xor/thread (r9: 128).
__global__ __launch_bounds__(512, 4) void k_gemm_part(const __bf16* __restrict__ A2,
                                                      const __bf16* __restrict__ B2,
                                                      int N, int K,
                                                      const float* __restrict__ rowN,
                                                      const float* __restrict__ colN,
                                                      float2* __restrict__ ms,
                                                      int* __restrict__ cnt,
                                                      int* __restrict__ candj,
                                                      float* __restrict__ candl) {
    __shared__ union {
        struct { unsigned short Ah[8192], Al[8192], Bh[8192], Bl[8192]; } st;
        float tile[128 * TSTR];          // 67584 B (> 65536 staging)
    } U;
    __shared__ float extraL[256];
    float* rnL = extraL;
    float* cnL = extraL + 128;

    int tid = threadIdx.x;
    int wid = tid >> 6, lane = tid & 63;
    int wm = (wid >> 2) * 64, wn = (wid & 3) * 32;
    int id = blockIdx.y * gridDim.x + blockIdx.x;
    int bn_i = ((id >> 6) << 3) | (id & 7);
    int bm_i = (id >> 3) & 7;
    int bm = bm_i * 128, bn = bn_i * 128;
    size_t K2 = 2 * (size_t)K;
    int nsteps = K >> 6;

    if (tid < 128) rnL[tid] = rowN[bm + tid];
    else if (tid < 256) cnL[tid - 128] = colN[bn + tid - 128];

    f32x4 acc[4][2];
    #pragma unroll
    for (int i = 0; i < 4; i++)
        #pragma unroll
        for (int j = 0; j < 2; j++) acc[i][j] = (f32x4){0.f, 0.f, 0.f, 0.f};

    int arr = wid & 3, hh = wid >> 2;
    char* arrB = (arr == 0) ? (char*)U.st.Ah : (arr == 1) ? (char*)U.st.Al
               : (arr == 2) ? (char*)U.st.Bh : (char*)U.st.Bl;
    const __bf16* gbase = (arr < 2) ? A2 : B2;
    int rbase = (arr < 2) ? bm : bn;
    int hilo = (arr & 1) ? K : 0;
    int r_in = lane >> 3;
    int cgo = ((lane & 7) ^ r_in) * 8;
    const __bf16* gw = gbase + (size_t)(rbase + hh * 64 + r_in) * K2 + hilo + cgo;
    int ldst = hh * 8192;
    size_t row8 = 8 * K2;

    int ra = lane & 15, q = lane >> 4;
    int aoff[4][2], boff[2][2];
    #pragma unroll
    for (int kh = 0; kh < 2; kh++) {
        #pragma unroll
        for (int i = 0; i < 4; i++) {
            int chunk = ((kh << 2) | q) ^ (ra & 7);
            aoff[i][kh] = (wm + i * 16 + ra) * 64 + chunk * 8;
        }
        #pragma unroll
        for (int j = 0; j < 2; j++) {
            int chunk = ((kh << 2) | q) ^ (ra & 7);
            boff[j][kh] = (wn + j * 16 + ra) * 64 + chunk * 8;
        }
    }
    const __bf16* AhE = (const __bf16*)U.st.Ah;
    const __bf16* AlE = (const __bf16*)U.st.Al;
    const __bf16* BhE = (const __bf16*)U.st.Bh;
    const __bf16* BlE = (const __bf16*)U.st.Bl;

    for (int ks = 0; ks < nsteps; ks++) {
        __syncthreads();
        #pragma unroll
        for (int p = 0; p < 8; p++)
            GLOAD_LDS(gw + (size_t)p * row8, arrB + ldst + p * 1024);
        gw += 64;
        __syncthreads();
        #pragma unroll
        for (int kh = 0; kh < 2; kh++) {
            bf16x8 ah[4], al[4];
            #pragma unroll
            for (int mi = 0; mi < 4; mi++) {
                ah[mi] = *(const bf16x8*)(AhE + aoff[mi][kh]);
                al[mi] = *(const bf16x8*)(AlE + aoff[mi][kh]);
            }
            #pragma unroll
            for (int ni = 0; ni < 2; ni++) {
                bf16x8 bh = *(const bf16x8*)(BhE + boff[ni][kh]);
                bf16x8 bl = *(const bf16x8*)(BlE + boff[ni][kh]);
                #pragma unroll
                for (int mi = 0; mi < 4; mi++) {
                    acc[mi][ni] = __builtin_amdgcn_mfma_f32_16x16x32_bf16(ah[mi], bh, acc[mi][ni], 0, 0, 0);
                    acc[mi][ni] = __builtin_amdgcn_mfma_f32_16x16x32_bf16(ah[mi], bl, acc[mi][ni], 0, 0, 0);
                    acc[mi][ni] = __builtin_amdgcn_mfma_f32_16x16x32_bf16(al[mi], bh, acc[mi][ni], 0, 0, 0);
                }
            }
        }
    }

    // ---- epilogue: acc -> LDS logit tile (staging arrays now dead) ----
    __syncthreads();                     // all waves done reading staged frags
    #pragma unroll
    for (int mi = 0; mi < 4; mi++) {
        #pragma unroll
        for (int ni = 0; ni < 2; ni++) {
            int cl = wn + ni * 16 + ra;
            float cn = cnL[cl];
            #pragma unroll
            for (int i = 0; i < 4; i++) {
                int rl = wm + mi * 16 + q * 4 + i;
                float sq = rnL[rl] + cn - 2.f * acc[mi][ni][i];
                U.tile[rl * TSTR + cl] = -TEMP * sqrtf(fmaxf(sq, 1e-12f));
            }
        }
    }
    __syncthreads();

    // ---- row scan: thread t -> row t>>2, quarter t&3 (32 cols) ----
    int r = tid >> 2, qt = tid & 3;
    const float4* rowp = (const float4*)&U.tile[r * TSTR + qt * 32];
    float4 v[8];
    float m = -1e30f;
    #pragma unroll
    for (int k = 0; k < 8; k++) {
        v[k] = rowp[k];
        m = fmaxf(m, max4(v[k]));
    }
    m = fmaxf(m, __shfl_xor(m, 1, 64));  // combine 4 quarters (lanes differ
    m = fmaxf(m, __shfl_xor(m, 2, 64));  // in bits 0-1) -> full 128-col max
    float s = 0.f;
    #pragma unroll
    for (int k = 0; k < 8; k++) {
        s += __expf(v[k].x - m) + __expf(v[k].y - m)
           + __expf(v[k].z - m) + __expf(v[k].w - m);
    }
    s += __shfl_xor(s, 1, 64);
    s += __shfl_xor(s, 2, 64);
    int gr = bm + r;
    if (qt == 0) ms[(size_t)gr * 64 + bn_i] = make_float2(m, s);
    float thr = m - LTHR;
    #pragma unroll
    for (int k = 0; k < 8; k++) {
        #pragma unroll
        for (int e = 0; e < 4; e++) {
            float lv = (e == 0) ? v[k].x : (e == 1) ? v[k].y : (e == 2) ? v[k].z : v[k].w;
            if (lv > thr) {
                int kk = atomicAdd(&cnt[gr], 1);
                if (kk < CCAP) {
                    candj[(size_t)gr * CCAP + kk] = bn + qt * 32 + k * 4 + e;
                    candl[(size_t)gr * CCAP + kk] = lv;
                }
            }
        }
    }
}

// ---- k_xsrc: exact softmax from partials + candidate eval + sparse gather --
__global__ __launch_bounds__(256) void k_xsrc(const float2* __restrict__ ms,
                                              const int* __restrict__ cnt,
                                              const int* __restrict__ candj,
                                              const float* __restrict__ candl,
                                              const float* __restrict__ asf,
                                              const float* __restrict__ W,
                                              const float* __restrict__ bias,
                                              __bf16* __restrict__ xsrc2,
                                              float* __restrict__ nx2_,
                                              float* __restrict__ preds) {
    __shared__ float sm[4];
    __shared__ float ss[4];
    __shared__ int   sidx[WCAP];
    __shared__ float swt[WCAP];
    __shared__ int   scnt;
    __shared__ float red[4][NC + 1];
    int row = blockIdx.x;
    int tid = threadIdx.x;
    int lane = tid & 63, wid = tid >> 6;
    if (tid == 0) scnt = 0;
    // all 4 waves redundantly reduce the 64 block partials
    float2 msv = ms[(size_t)row * 64 + lane];
    float wmx = wave_max(msv.x);
    if (lane == 0) sm[wid] = wmx;
    __syncthreads();                     // also covers scnt=0
    float M = fmaxf(fmaxf(sm[0], sm[1]), fmaxf(sm[2], sm[3]));
    float sp = msv.y * __expf(msv.x - M);
    float wsv = wave_sum(sp);
    if (lane == 0) ss[wid] = wsv;
    __syncthreads();
    float inv = 1.0f / ss[0];            // each wave computed the full sum
    int n = cnt[row]; n = n < CCAP ? n : CCAP;
    for (int i = tid; i < n; i += 256) {
        float w = __expf(candl[(size_t)row * CCAP + i] - M) * inv;
        if (w > 1e-8f) {
            int k = atomicAdd(&scnt, 1);
            if (k < WCAP) { sidx[k] = candj[(size_t)row * CCAP + i]; swt[k] = w; }
        }
    }
    __syncthreads();
    int cw = scnt < WCAP ? scnt : WCAP;
    int c = tid * 4;
    float sx = 0.f, sy = 0.f, sz = 0.f, sw = 0.f;
    for (int i = 0; i < cw; i++) {
        float wg = swt[i];
        float4 v = *(const float4*)(asf + (size_t)sidx[i] * DIM + c);
        sx += wg * v.x; sy += wg * v.y; sz += wg * v.z; sw += wg * v.w;
    }
    // ---- fused epilogue: split + norm + preds ----
    bf16x4 h, l;
    h[0] = split_hi(sx); l[0] = split_lo(sx);
    h[1] = split_hi(sy); l[1] = split_lo(sy);
    h[2] = split_hi(sz); l[2] = split_lo(sz);
    h[3] = split_hi(sw); l[3] = split_lo(sw);
    *(bf16x4*)(xsrc2 + (size_t)row * 2048 + c) = h;
    *(bf16x4*)(xsrc2 + (size_t)row * 2048 + 1024 + c) = l;
    float accn = sx * sx + sy * sy + sz * sz + sw * sw;
    float accp[NC];
    #pragma unroll
    for (int cc = 0; cc < NC; cc++)
        accp[cc] = sx * W[(c + 0) * NC + cc] + sy * W[(c + 1) * NC + cc]
                 + sz * W[(c + 2) * NC + cc] + sw * W[(c + 3) * NC + cc];
    accn = wave_sum(accn);
    #pragma unroll
    for (int cc = 0; cc < NC; cc++) accp[cc] = wave_sum(accp[cc]);
    if (lane == 0) {
        red[wid][0] = accn;
        #pragma unroll
        for (int cc = 0; cc < NC; cc++) red[wid][1 + cc] = accp[cc];
    }
    __syncthreads();
    if (tid == 0) {
        nx2_[row] = red[0][0] + red[1][0] + red[2][0] + red[3][0];
        float lo[NC];
        float m = -1e30f;
        #pragma unroll
        for (int cc = 0; cc < NC; cc++) {
            lo[cc] = red[0][1 + cc] + red[1][1 + cc] + red[2][1 + cc] + red[3][1 + cc]
                   + bias[cc];
            m = fmaxf(m, lo[cc]);
        }
        float ssum = 0.f;
        #pragma unroll
        for (int cc = 0; cc < NC; cc++) {
            lo[cc] = __expf(lo[cc] - m);
            ssum += lo[cc];
        }
        float iv = 1.0f / ssum;
        #pragma unroll
        for (int cc = 0; cc < NC; cc++) preds[(size_t)row * NC + cc] = lo[cc] * iv;
    }
}

// ------- label softmax + y, 2 rows/block, float4-vectorized ------------------
__global__ __launch_bounds__(256) void k_lab_softmax_y(const float* __restrict__ S,
                                                       const float* __restrict__ predsG,
                                                       const float* __restrict__ M2Tt,
                                                       const float* __restrict__ atlt,
                                                       float* __restrict__ y) {
    int r0 = blockIdx.x * 2, r1 = r0 + 1;
    float pr0[NC], pr1[NC];
    #pragma unroll
    for (int c = 0; c < NC; c++) {
        pr0[c] = TEMP * predsG[(size_t)r0 * NC + c];
        pr1[c] = TEMP * predsG[(size_t)r1 * NC + c];
    }
    const float4* s0 = (const float4*)(S + (size_t)r0 * NS);
    const float4* s1 = (const float4*)(S + (size_t)r1 * NS);
    const float4* M2 = (const float4*)M2Tt;    // [NC][2048]
    const float4* AT = (const float4*)atlt;    // [NC][2048]
    float4 v0[NS / 1024], v1[NS / 1024];       // 8 each
    float m0 = -1e30f, m1 = -1e30f;
    #pragma unroll
    for (int u = 0; u < NS / 1024; u++) {
        int j4 = threadIdx.x + u * 256;
        float4 a = s0[j4], b = s1[j4];
        float4 lab0 = make_float4(0.f, 0.f, 0.f, 0.f);
        float4 lab1 = make_float4(0.f, 0.f, 0.f, 0.f);
        #pragma unroll
        for (int c = 0; c < NC; c++) {
            float4 mv = M2[c * 2048 + j4];
            lab0.x += pr0[c] * mv.x; lab0.y += pr0[c] * mv.y;
            lab0.z += pr0[c] * mv.z; lab0.w += pr0[c] * mv.w;
            lab1.x += pr1[c] * mv.x; lab1.y += pr1[c] * mv.y;
            lab1.z += pr1[c] * mv.z; lab1.w += pr1[c] * mv.w;
        }
        a.x -= lab0.x; a.y -= lab0.y;
        a.z -= lab0.z; a.w -= lab0.w;
        b.x -= lab1.x; b.y -= lab1.y;
        b.z -= lab1.z; b.w -= lab1.w;
        v0[u] = a; v1[u] = b;
        m0 = fmaxf(m0, fmaxf(fmaxf(a.x, a.y), fmaxf(a.z, a.w)));
        m1 = fmaxf(m1, fmaxf(fmaxf(b.x, b.y), fmaxf(b.z, b.w)));
    }
    __shared__ float sm[2][4];
    __shared__ float ss[2][4];
    __shared__ float yred[4][2][NC];
    int lane = threadIdx.x & 63, wid = threadIdx.x >> 6;
    float wm0 = wave_max(m0), wm1 = wave_max(m1);
    if (lane == 0) { sm[0][wid] = wm0; sm[1][wid] = wm1; }
    __syncthreads();
    float bm0 = fmaxf(fmaxf(sm[0][0], sm[0][1]), fmaxf(sm[0][2], sm[0][3]));
    float bm1 = fmaxf(fmaxf(sm[1][0], sm[1][1]), fmaxf(sm[1][2], sm[1][3]));
    float ls0 = 0.f, ls1 = 0.f;
    #pragma unroll
    for (int u = 0; u < NS / 1024; u++) {
        float4 a = v0[u], b = v1[u];
        a.x = __expf(a.x - bm0); a.y = __expf(a.y - bm0);
        a.z = __expf(a.z - bm0); a.w = __expf(a.w - bm0);
        b.x = __expf(b.x - bm1); b.y = __expf(b.y - bm1);
        b.z = __expf(b.z - bm1); b.w = __expf(b.w - bm1);
        v0[u] = a; v1[u] = b;
        ls0 += a.x + a.y + a.z + a.w;
        ls1 += b.x + b.y + b.z + b.w;
    }
    float ws0 = wave_sum(ls0), ws1 = wave_sum(ls1);
    if (lane == 0) { ss[0][wid] = ws0; ss[1][wid] = ws1; }
    __syncthreads();
    float inv0 = 1.0f / (ss[0][0] + ss[0][1] + ss[0][2] + ss[0][3]);
    float inv1 = 1.0f / (ss[1][0] + ss[1][1] + ss[1][2] + ss[1][3]);
    float y0[NC] = {}, y1[NC] = {};
    #pragma unroll
    for (int u = 0; u < NS / 1024; u++) {
        int j4 = threadIdx.x + u * 256;
        float4 a = v0[u], b = v1[u];
        #pragma unroll
        for (int c = 0; c < NC; c++) {
            float4 av = AT[c * 2048 + j4];
            y0[c] += a.x * av.x + a.y * av.y + a.z * av.z + a.w * av.w;
            y1[c] += b.x * av.x + b.y * av.y + b.z * av.z + b.w * av.w;
        }
    }
    #pragma unroll
    for (int c = 0; c < NC; c++) {
        y0[c] = wave_sum(y0[c]) * inv0;
        y1[c] = wave_sum(y1[c]) * inv1;
    }
    if (lane == 0) {
        #pragma unroll
        for (int c = 0; c < NC; c++) { yred[wid][0][c] = y0[c]; yred[wid][1][c] = y1[c]; }
    }
    __syncthreads();
    if (threadIdx.x < 2 * NC) {
        int r = threadIdx.x / NC, c = threadIdx.x - r * NC;
        y[(size_t)(r0 + r) * NC + c] = yred[0][r][c] + yred[1][r][c] + yred[2][r][c] + yred[3][r][c];
    }
}

extern "C" void kernel_launch(void* const* d_in, const int* in_sizes, int n_in,
                              void* d_out, int out_size, void* d_ws, size_t ws_size,
                              hipStream_t stream) {
    const float* x    = (const float*)d_in[0];   // [1024, 32, 32]
    const float* tf   = (const float*)d_in[1];   // [8192, 1024]
    const float* asf  = (const float*)d_in[2];   // [8192, 1024]
    const float* sf   = (const float*)d_in[3];   // [8192, 1024]
    const float* shdl = (const float*)d_in[4];   // [8192, 10]
    const float* atl  = (const float*)d_in[5];   // [8192, 10]
    const float* sld  = (const float*)d_in[6];   // [10, 10]
    const float* W    = (const float*)d_in[7];   // [1024, 10]
    const float* bias = (const float*)d_in[8];   // [10]
    float* y = (float*)d_out;                    // [1024, 10]

    char* wsb = (char*)d_ws;
    // Region lifetimes:
    //  R0 @0 (32 MiB): [G1 phase] candj(2M) candl(2M) ms(512K) cnt(4K)
    //                  [G3 phase] S (32 MiB) - overwrites cand data (dead)
    //  R1 @32 (32 MiB): tf2 (dead after G1)
    //  R2 @64 (32 MiB): sf2 (written by k_prep0, read by G3)
    int*    candj = (int*)(wsb);
    float*  candl = (float*)(wsb + (2u << 20));
    float2* ms    = (float2*)(wsb + (4u << 20));
    int*    cnt   = (int*)(wsb + (4u << 20) + (512u << 10));
    float*  S     = (float*)(wsb);
    __bf16* tf2   = (__bf16*)(wsb + (32u << 20));
    __bf16* sf2   = (__bf16*)(wsb + (64u << 20));
    __bf16* x2    = (__bf16*)(wsb + (96u << 20));           // 4 MiB
    __bf16* xsrc2 = (__bf16*)(wsb + (100u << 20));          // 4 MiB
    float*  nt_   = (float*)(wsb + (108u << 20));
    float*  ns_   = nt_ + NT;
    float*  nx_   = ns_ + NS;
    float*  nx2_  = nx_ + B_ROWS;
    float*  preds = nx2_ + B_ROWS;
    float*  M2Tt  = preds + B_ROWS * NC;                    // [10][8192]
    float*  atlt  = M2Tt + NS * NC;                         // [10][8192]

    // K0: conv_norm(x|tf|sf) 8 rows/block + prep_labels + zero cnt
    {
        int nblk = B_ROWS / PREP_RPB + NT / PREP_RPB + NS / PREP_RPB + NS / 256;
        k_prep0<<<nblk, 256, 0, stream>>>(x, tf, sf, sld, shdl, atl,
                                          x2, tf2, sf2, nx_, nt_, ns_, M2Tt, atlt,
                                          cnt);
    }

    // G1 (partial): per-block softmax stats + candidates; no S materialization
    {
        dim3 g(NT / 128, B_ROWS / 128, 1);
        k_gemm_part<<<g, 512, 0, stream>>>(x2, tf2, NT, DIM, nx_, nt_,
                                           ms, cnt, candj, candl);
    }

    // k_xsrc: exact softmax merge + sparse gather (reads ~5 MB, was 32 MB)
    k_xsrc<<<B_ROWS, 256, 0, stream>>>(ms, cnt, candj, candl, asf, W, bias,
                                       xsrc2, nx2_, preds);

    // G3: S = logits(-TEMP*d(xsrc, sf))  (M=1024, N=8192, K=1024) -> R0
    {
        dim3 g(NS / 128, B_ROWS / 128, 1);
        k_gemm3L<<<g, 512, 0, stream>>>(xsrc2, sf2, S, NS, DIM, nx2_, ns_);
    }
    // label softmax (with M2T term) + y, 2 rows/block (vectorized)
    k_lab_softmax_y<<<B_ROWS / 2, 256, 0, stream>>>(S, preds, M2Tt, atlt, y);
}